// Round 4
// baseline (201.117 us; speedup 1.0000x reference)
//
#include <hip/hip_runtime.h>
#include <hip/hip_bf16.h>
#include <stdint.h>

#define D_MODEL 1024
#define NHEADS  16
#define DK      64
#define SEQ     2048
#define BATCH   2

typedef __bf16 bf16x8 __attribute__((ext_vector_type(8)));
typedef __bf16 bf16x4 __attribute__((ext_vector_type(4)));
typedef float  f32x4  __attribute__((ext_vector_type(4)));

__device__ __forceinline__ void async_copy16(const void* g, void* l) {
  __builtin_amdgcn_global_load_lds(
      (__attribute__((address_space(1))) void*)g,
      (__attribute__((address_space(3))) void*)l, 16, 0, 0);
}

// ---------------- fused casts: 3 x MD + 4 x WD arrays ----------------
__global__ void cast_all(const float* __restrict__ q, const float* __restrict__ k,
                         const float* __restrict__ v, const float* __restrict__ wq,
                         const float* __restrict__ wk, const float* __restrict__ wv,
                         const float* __restrict__ wo,
                         __bf16* __restrict__ oq, __bf16* __restrict__ ok,
                         __bf16* __restrict__ ov, __bf16* __restrict__ owq,
                         __bf16* __restrict__ owk, __bf16* __restrict__ owv,
                         __bf16* __restrict__ owo) {
  constexpr unsigned Q4 = (unsigned)(BATCH * SEQ * D_MODEL) / 4;  // 2^20
  constexpr unsigned W4 = (unsigned)(D_MODEL * D_MODEL) / 4;      // 2^18
  unsigned i = blockIdx.x * 256u + threadIdx.x;
  const float* in; __bf16* out; unsigned off;
  if (i < 3 * Q4) {
    unsigned z = i >> 20; off = i & (Q4 - 1);
    in  = z == 0 ? q : z == 1 ? k : v;
    out = z == 0 ? oq : z == 1 ? ok : ov;
  } else {
    unsigned j = i - 3 * Q4;
    unsigned z = j >> 18; off = j & (W4 - 1);
    in  = z == 0 ? wq : z == 1 ? wk : z == 2 ? wv : wo;
    out = z == 0 ? owq : z == 1 ? owk : z == 2 ? owv : owo;
  }
  float4 val = *(const float4*)(in + (size_t)off * 4);
  bf16x4 o;
  o.x = (__bf16)val.x; o.y = (__bf16)val.y; o.z = (__bf16)val.z; o.w = (__bf16)val.w;
  *(bf16x4*)(out + (size_t)off * 4) = o;
}

// ---------------- proj GEMM + fused V transpose (R3 body, proven) ----------------
__global__ __launch_bounds__(256, 3)
void gemm_proj(const __bf16* __restrict__ A0, const __bf16* __restrict__ A1, const __bf16* __restrict__ A2,
               const __bf16* __restrict__ B0, const __bf16* __restrict__ B1, const __bf16* __restrict__ B2,
               __bf16* __restrict__ Qp, __bf16* __restrict__ Kp, __bf16* __restrict__ Vt) {
  constexpr int K = D_MODEL, N = D_MODEL;
  const int zi = blockIdx.z;
  const __bf16* A; const __bf16* Bm;
  if (zi == 0)      { A = A0; Bm = B0; }
  else if (zi == 1) { A = A1; Bm = B1; }
  else              { A = A2; Bm = B2; }

  __shared__ __align__(16) char smem[34816];
  __bf16* Ash = (__bf16*)smem;                 // [128][64] = 16 KB
  __bf16* Bsh = (__bf16*)(smem + 16384);       // [128][64] = 16 KB
  __bf16* Tr  = (__bf16*)smem;                 // epilogue alias [128][136] = 34816 B

  const int tid  = threadIdx.x;
  const int lane = tid & 63;
  const int w    = tid >> 6;
  const int quad = lane >> 4;
  const int l16  = lane & 15;
  const int wr   = w >> 1, wc = w & 1;
  const size_t m0 = (size_t)blockIdx.x * 128;   // M on x: same-A blocks share XCD
  const size_t n0 = (size_t)blockIdx.y * 128;

  f32x4 acc[4][4] = {};

  for (int k0 = 0; k0 < K; k0 += 64) {
#pragma unroll
    for (int it = 0; it < 4; ++it) {
      int slot = tid + it * 256;
      int row = slot >> 3, ch = slot & 7;
      async_copy16(A + (m0 + row) * K + k0 + ((ch ^ (row & 7)) * 8), &Ash[slot * 8]);
    }
#pragma unroll
    for (int it = 0; it < 4; ++it) {
      int slot = tid + it * 256;
      int row = slot >> 3, ch = slot & 7;
      async_copy16(Bm + (n0 + row) * K + k0 + ((ch ^ (row & 7)) * 8), &Bsh[slot * 8]);
    }
    __syncthreads();
#pragma unroll
    for (int kk = 0; kk < 2; ++kk) {
      bf16x8 af[4], bfr[4];
#pragma unroll
      for (int i = 0; i < 4; ++i) {
        int row = wr * 64 + i * 16 + l16;
        af[i] = *(const bf16x8*)&Ash[row * 64 + (((kk * 4 + quad) ^ (row & 7)) * 8)];
      }
#pragma unroll
      for (int j = 0; j < 4; ++j) {
        int row = wc * 64 + j * 16 + l16;
        bfr[j] = *(const bf16x8*)&Bsh[row * 64 + (((kk * 4 + quad) ^ (row & 7)) * 8)];
      }
#pragma unroll
      for (int i = 0; i < 4; ++i)
#pragma unroll
        for (int j = 0; j < 4; ++j)
          acc[i][j] = __builtin_amdgcn_mfma_f32_16x16x32_bf16(af[i], bfr[j], acc[i][j], 0, 0, 0);
    }
    __syncthreads();
  }

  if (zi != 2) {
    __bf16* C = (zi == 0) ? Qp : Kp;
#pragma unroll
    for (int i = 0; i < 4; ++i)
#pragma unroll
      for (int j = 0; j < 4; ++j)
#pragma unroll
        for (int r = 0; r < 4; ++r) {
          size_t row = m0 + wr * 64 + i * 16 + quad * 4 + r;
          size_t col = n0 + wc * 64 + j * 16 + l16;
          C[row * N + col] = (__bf16)acc[i][j][r];
        }
  } else {
    // transpose through LDS: Tr[d_local * 136 + s_local] (aliased; loop-end
    // __syncthreads already fenced the last Ash/Bsh reads)
#pragma unroll
    for (int i = 0; i < 4; ++i)
#pragma unroll
      for (int j = 0; j < 4; ++j)
#pragma unroll
        for (int r = 0; r < 4; ++r)
          Tr[(wc * 64 + j * 16 + l16) * 136 + (wr * 64 + i * 16 + quad * 4 + r)] =
              (__bf16)acc[i][j][r];
    __syncthreads();
    const int b_  = (int)(m0 >> 11);        // m0 / SEQ  (tile never crosses batch)
    const int sl0 = (int)(m0 & 2047);
#pragma unroll
    for (int it = 0; it < 8; ++it) {
      int slot = tid + it * 256;
      int d = slot >> 4, sc = slot & 15;
      *(int4*)&Vt[((size_t)(b_ * D_MODEL) + n0 + d) * SEQ + sl0 + sc * 8] =
          *(const int4*)&Tr[d * 136 + sc * 8];
    }
  }
}

// ---------------- out-proj GEMM (R3 body, proven) ----------------
__global__ __launch_bounds__(256, 2)
void gemm_out(const __bf16* __restrict__ A, const __bf16* __restrict__ Bm,
              float* __restrict__ C) {
  constexpr int BM = 64, BN = 128, K = D_MODEL, N = D_MODEL;
  __shared__ __bf16 Ash[BM * 64];   //  8 KB
  __shared__ __bf16 Bsh[BN * 64];   // 16 KB

  const int tid  = threadIdx.x;
  const int lane = tid & 63;
  const int w    = tid >> 6;
  const int quad = lane >> 4;
  const int l16  = lane & 15;
  const int wr   = w >> 1, wc = w & 1;
  const size_t m0 = (size_t)blockIdx.x * BM;
  const size_t n0 = (size_t)blockIdx.y * BN;

  f32x4 acc[2][4] = {};

  for (int k0 = 0; k0 < K; k0 += 64) {
#pragma unroll
    for (int it = 0; it < 2; ++it) {
      int slot = tid + it * 256;
      int row = slot >> 3, ch = slot & 7;
      async_copy16(A + (m0 + row) * K + k0 + ((ch ^ (row & 7)) * 8), &Ash[slot * 8]);
    }
#pragma unroll
    for (int it = 0; it < 4; ++it) {
      int slot = tid + it * 256;
      int row = slot >> 3, ch = slot & 7;
      async_copy16(Bm + (n0 + row) * K + k0 + ((ch ^ (row & 7)) * 8), &Bsh[slot * 8]);
    }
    __syncthreads();
#pragma unroll
    for (int kk = 0; kk < 2; ++kk) {
      bf16x8 af[2], bfr[4];
#pragma unroll
      for (int i = 0; i < 2; ++i) {
        int row = wr * 32 + i * 16 + l16;
        af[i] = *(const bf16x8*)&Ash[row * 64 + (((kk * 4 + quad) ^ (row & 7)) * 8)];
      }
#pragma unroll
      for (int j = 0; j < 4; ++j) {
        int row = wc * 64 + j * 16 + l16;
        bfr[j] = *(const bf16x8*)&Bsh[row * 64 + (((kk * 4 + quad) ^ (row & 7)) * 8)];
      }
#pragma unroll
      for (int i = 0; i < 2; ++i)
#pragma unroll
        for (int j = 0; j < 4; ++j)
          acc[i][j] = __builtin_amdgcn_mfma_f32_16x16x32_bf16(af[i], bfr[j], acc[i][j], 0, 0, 0);
    }
    __syncthreads();
  }

#pragma unroll
  for (int i = 0; i < 2; ++i)
#pragma unroll
    for (int j = 0; j < 4; ++j)
#pragma unroll
      for (int r = 0; r < 4; ++r) {
        size_t row = m0 + wr * 32 + i * 16 + quad * 4 + r;
        size_t col = n0 + wc * 64 + j * 16 + l16;
        C[row * N + col] = acc[i][j][r];
      }
}

// ---------------- causal flash attention ----------------
// R4: QBLK=128 via 8-wave (512-thread) blocks. Per-wave math identical to the
// proven R1 body (qh now 0..3). Block-iterations 16896 -> 8704: per-iter
// barrier/stage overhead amortizes over 2x MFMA. 512 blocks, 2/CU resident,
// 16 waves/CU (4/SIMD). LDS 53248: Kb16K + Vb16K + Ps20.5K; epilogue scratch
// aliased over dead Kb/Vb.
#define PS_W 40

__global__ __launch_bounds__(512, 4)
void attn_kernel(const __bf16* __restrict__ Qp, const __bf16* __restrict__ Kp,
                 const __bf16* __restrict__ Vt, __bf16* __restrict__ Xo) {
  __shared__ __align__(16) char smem[53248];
  __bf16* Kb  = (__bf16*)smem;                 // [2 dbuf][2 kd][64][32] = 16384 B
  __bf16* Vb  = (__bf16*)(smem + 16384);       // [2 dbuf][2 kd][64][32] = 16384 B
  __bf16* Ps  = (__bf16*)(smem + 32768);       // [8*32][PS_W]           = 20480 B
  float*  Xch  = (float*)smem;                 // epilogue alias [4*16][66] = 16896 B
  float*  Lsum = (float*)(smem + 16896);       // epilogue alias [4*32]     =   512 B

  const int tid  = threadIdx.x;
  const int lane = tid & 63;
  const int w    = tid >> 6;                 // 0..7
  const int qh   = w >> 1, kh = w & 1;       // qh 0..3 (32 q-rows each), kh splits K-cols
  const int quad = lane >> 4;
  const int l16  = lane & 15;
  const int bh   = blockIdx.x;               // fastest -> XCD spread
  const int qt   = 15 - blockIdx.y;          // longest blocks dispatch first
  const int b    = bh >> 4, h = bh & 15;
  const int q0   = qt * 128;
  const size_t baseRow = (size_t)b * SEQ;
  const int colBase = h * DK;

  // staging: one K-async + one V-async per thread (512 x 16B = 8KB per tile)
  const int skd  = tid >> 8;                               // col-half (kd)
  const int srow = (tid >> 2) & 63;                        // tile row
  const int sk   = (tid & 3) * 8;                          // linear LDS dest slot
  const int skz  = (((tid & 3) ^ ((tid >> 3) & 3)) * 8);   // inverse-swizzled global slot
  const int swz  = (l16 >> 1) & 3;                         // read-side slot XOR

  const float c1 = 0.18033688011f;           // 0.125 * log2(e)
  const float c2 = -23.083120654f;           // constant softmax shift

  bf16x8 aq[2][2];
  {
    const __bf16* qrow = Qp + (baseRow + q0 + qh * 32 + l16) * D_MODEL + colBase;
#pragma unroll
    for (int mt = 0; mt < 2; ++mt)
#pragma unroll
      for (int kd = 0; kd < 2; ++kd)
        aq[mt][kd] = *(const bf16x8*)(qrow + (size_t)mt * 16 * D_MODEL + kd * 32 + quad * 8);
  }

  f32x4 oacc[2][4] = {};
  float plsum[2][4] = {};

  const int jmax = 2 * qt + 1;

  {  // prologue: stage j=0 into buf 0 (source pre-swizzled, LDS dest linear)
    async_copy16(Kp + (baseRow + srow) * D_MODEL + colBase + skd * 32 + skz,
                 &Kb[skd * 2048 + srow * 32 + sk]);
    async_copy16(Vt + ((size_t)b * D_MODEL + colBase + srow) * SEQ + skd * 32 + skz,
                 &Vb[skd * 2048 + srow * 32 + sk]);
  }

  for (int j = 0; j <= jmax; ++j) {
    const int bf = j & 1;
    __syncthreads();

    if (j < jmax) {
      const int nb = bf ^ 1;
      async_copy16(Kp + (baseRow + (size_t)(j + 1) * 64 + srow) * D_MODEL + colBase + skd * 32 + skz,
                   &Kb[(nb * 2 + skd) * 2048 + srow * 32 + sk]);
      async_copy16(Vt + ((size_t)b * D_MODEL + colBase + srow) * SEQ + (size_t)(j + 1) * 64 + skd * 32 + skz,
                   &Vb[(nb * 2 + skd) * 2048 + srow * 32 + sk]);
    }

    f32x4 sacc[2][2] = {};
    __builtin_amdgcn_s_setprio(1);
#pragma unroll
    for (int kd = 0; kd < 2; ++kd) {
      bf16x8 bk0 = *(const bf16x8*)&Kb[(bf * 2 + kd) * 2048 + (kh * 32 + l16) * 32 + (quad ^ swz) * 8];
      bf16x8 bk1 = *(const bf16x8*)&Kb[(bf * 2 + kd) * 2048 + (kh * 32 + 16 + l16) * 32 + (quad ^ swz) * 8];
      sacc[0][0] = __builtin_amdgcn_mfma_f32_16x16x32_bf16(aq[0][kd], bk0, sacc[0][0], 0, 0, 0);
      sacc[0][1] = __builtin_amdgcn_mfma_f32_16x16x32_bf16(aq[0][kd], bk1, sacc[0][1], 0, 0, 0);
      sacc[1][0] = __builtin_amdgcn_mfma_f32_16x16x32_bf16(aq[1][kd], bk0, sacc[1][0], 0, 0, 0);
      sacc[1][1] = __builtin_amdgcn_mfma_f32_16x16x32_bf16(aq[1][kd], bk1, sacc[1][1], 0, 0, 0);
    }
    __builtin_amdgcn_s_setprio(0);

    const bool diag = (j >= 2 * qt);   // last two tiles intersect the diagonal band
#pragma unroll
    for (int mt = 0; mt < 2; ++mt)
#pragma unroll
      for (int nt2 = 0; nt2 < 2; ++nt2)
#pragma unroll
        for (int r = 0; r < 4; ++r) {
          float arg = fmaf(sacc[mt][nt2][r], c1, c2);
          if (diag) {
            int rowg = q0 + qh * 32 + mt * 16 + quad * 4 + r;
            int colg = j * 64 + kh * 32 + nt2 * 16 + l16;
            if (colg > rowg) arg = -1e30f;
          }
          float p = __builtin_amdgcn_exp2f(arg);
          plsum[mt][r] += p;
          Ps[(w * 32 + mt * 16 + quad * 4 + r) * PS_W + nt2 * 16 + l16] = (__bf16)p;
        }

    bf16x8 bv[4];
    __builtin_amdgcn_s_setprio(1);
#pragma unroll
    for (int nt = 0; nt < 4; ++nt)
      bv[nt] = *(const bf16x8*)&Vb[(bf * 2 + kh) * 2048 + (nt * 16 + l16) * 32 + (quad ^ swz) * 8];
#pragma unroll
    for (int mt = 0; mt < 2; ++mt) {
      bf16x8 ap = *(const bf16x8*)&Ps[(w * 32 + mt * 16 + l16) * PS_W + quad * 8];
#pragma unroll
      for (int nt = 0; nt < 4; ++nt)
        oacc[mt][nt] = __builtin_amdgcn_mfma_f32_16x16x32_bf16(ap, bv[nt], oacc[mt][nt], 0, 0, 0);
    }
    __builtin_amdgcn_s_setprio(0);
  }

  float lred[2][4];
#pragma unroll
  for (int mt = 0; mt < 2; ++mt)
#pragma unroll
    for (int r = 0; r < 4; ++r) {
      float l = plsum[mt][r];
      for (int off = 1; off < 16; off <<= 1) l += __shfl_xor(l, off, 64);
      lred[mt][r] = l;
    }

#pragma unroll
  for (int mt = 0; mt < 2; ++mt) {   // FULLY UNROLLED (runtime mt index spills accumulators)
    __syncthreads();                 // fences Kb/Vb reads before alias writes
    if (kh == 1) {
#pragma unroll
      for (int nt = 0; nt < 4; ++nt)
#pragma unroll
        for (int r = 0; r < 4; ++r)
          Xch[(qh * 16 + quad * 4 + r) * 66 + nt * 16 + l16] = oacc[mt][nt][r];
#pragma unroll
      for (int r = 0; r < 4; ++r)
        Lsum[qh * 32 + mt * 16 + quad * 4 + r] = lred[mt][r];
    }
    __syncthreads();
    if (kh == 0) {
#pragma unroll
      for (int r = 0; r < 4; ++r) {
        float lt  = lred[mt][r] + Lsum[qh * 32 + mt * 16 + quad * 4 + r];
        float inv = 1.0f / lt;
        size_t row = baseRow + q0 + qh * 32 + mt * 16 + quad * 4 + r;
#pragma unroll
        for (int nt = 0; nt < 4; ++nt) {
          float o = oacc[mt][nt][r] + Xch[(qh * 16 + quad * 4 + r) * 66 + nt * 16 + l16];
          Xo[row * D_MODEL + colBase + nt * 16 + l16] = (__bf16)(o * inv);
        }
      }
    }
  }
}

// ---------------- launch ----------------
extern "C" void kernel_launch(void* const* d_in, const int* in_sizes, int n_in,
                              void* d_out, int out_size, void* d_ws, size_t ws_size,
                              hipStream_t stream) {
  const float* q  = (const float*)d_in[0];
  const float* k  = (const float*)d_in[1];
  const float* v  = (const float*)d_in[2];
  const float* wq = (const float*)d_in[3];
  const float* wk = (const float*)d_in[4];
  const float* wv = (const float*)d_in[5];
  const float* wo = (const float*)d_in[6];
  float* out = (float*)d_out;

  const size_t MD = (size_t)BATCH * SEQ * D_MODEL;
  const size_t WD = (size_t)D_MODEL * D_MODEL;
  __bf16* ws  = (__bf16*)d_ws;
  __bf16* Qp  = ws;
  __bf16* Kp  = Qp + MD;
  __bf16* Vt  = Kp + MD;
  __bf16* Xa  = Vt + MD;
  __bf16* qbf = Xa + MD;
  __bf16* kbf = qbf + MD;
  __bf16* vbf = kbf + MD;
  __bf16* wqb = vbf + MD;
  __bf16* wkb = wqb + WD;
  __bf16* wvb = wkb + WD;
  __bf16* wob = wvb + WD;

  // 1) casts: 3*MD/4 + 4*WD/4 = 4 Mi float4 -> 16384 blocks
  cast_all<<<16384, 256, 0, stream>>>(q, k, v, wq, wk, wv, wo,
                                      qbf, kbf, vbf, wqb, wkb, wvb, wob);

  // 2) Q/K/V projections (V written directly transposed)
  gemm_proj<<<dim3(32, 8, 3), 256, 0, stream>>>(
      qbf, kbf, vbf, wqb, wkb, wvb, Qp, Kp, Vt);

  // 3) causal attention: 512 blocks of 512 threads (bh fastest, qt descending)
  attn_kernel<<<dim3(BATCH * NHEADS, 16), 512, 0, stream>>>(Qp, Kp, Vt, Xa);

  // 4) output projection -> f32 out
  gemm_out<<<dim3(64, 8), 256, 0, stream>>>(Xa, wob, out);
}

// Round 5
// 179.209 us; speedup vs baseline: 1.1222x; 1.1222x over previous
//
#include <hip/hip_runtime.h>
#include <hip/hip_bf16.h>
#include <stdint.h>

#define D_MODEL 1024
#define NHEADS  16
#define DK      64
#define SEQ     2048
#define BATCH   2

typedef __bf16 bf16x8 __attribute__((ext_vector_type(8)));
typedef __bf16 bf16x4 __attribute__((ext_vector_type(4)));
typedef float  f32x4  __attribute__((ext_vector_type(4)));

__device__ __forceinline__ void async_copy16(const void* g, void* l) {
  __builtin_amdgcn_global_load_lds(
      (__attribute__((address_space(1))) void*)g,
      (__attribute__((address_space(3))) void*)l, 16, 0, 0);
}

// ---------------- fused casts: 3 x MD + 4 x WD arrays ----------------
__global__ void cast_all(const float* __restrict__ q, const float* __restrict__ k,
                         const float* __restrict__ v, const float* __restrict__ wq,
                         const float* __restrict__ wk, const float* __restrict__ wv,
                         const float* __restrict__ wo,
                         __bf16* __restrict__ oq, __bf16* __restrict__ ok,
                         __bf16* __restrict__ ov, __bf16* __restrict__ owq,
                         __bf16* __restrict__ owk, __bf16* __restrict__ owv,
                         __bf16* __restrict__ owo) {
  constexpr unsigned Q4 = (unsigned)(BATCH * SEQ * D_MODEL) / 4;  // 2^20
  constexpr unsigned W4 = (unsigned)(D_MODEL * D_MODEL) / 4;      // 2^18
  unsigned i = blockIdx.x * 256u + threadIdx.x;
  const float* in; __bf16* out; unsigned off;
  if (i < 3 * Q4) {
    unsigned z = i >> 20; off = i & (Q4 - 1);
    in  = z == 0 ? q : z == 1 ? k : v;
    out = z == 0 ? oq : z == 1 ? ok : ov;
  } else {
    unsigned j = i - 3 * Q4;
    unsigned z = j >> 18; off = j & (W4 - 1);
    in  = z == 0 ? wq : z == 1 ? wk : z == 2 ? wv : wo;
    out = z == 0 ? owq : z == 1 ? owk : z == 2 ? owv : owo;
  }
  float4 val = *(const float4*)(in + (size_t)off * 4);
  bf16x4 o;
  o.x = (__bf16)val.x; o.y = (__bf16)val.y; o.z = (__bf16)val.z; o.w = (__bf16)val.w;
  *(bf16x4*)(out + (size_t)off * 4) = o;
}

// ---------------- proj GEMM + fused V transpose (R3 body, proven) ----------------
__global__ __launch_bounds__(256, 3)
void gemm_proj(const __bf16* __restrict__ A0, const __bf16* __restrict__ A1, const __bf16* __restrict__ A2,
               const __bf16* __restrict__ B0, const __bf16* __restrict__ B1, const __bf16* __restrict__ B2,
               __bf16* __restrict__ Qp, __bf16* __restrict__ Kp, __bf16* __restrict__ Vt) {
  constexpr int K = D_MODEL, N = D_MODEL;
  const int zi = blockIdx.z;
  const __bf16* A; const __bf16* Bm;
  if (zi == 0)      { A = A0; Bm = B0; }
  else if (zi == 1) { A = A1; Bm = B1; }
  else              { A = A2; Bm = B2; }

  __shared__ __align__(16) char smem[34816];
  __bf16* Ash = (__bf16*)smem;                 // [128][64] = 16 KB
  __bf16* Bsh = (__bf16*)(smem + 16384);       // [128][64] = 16 KB
  __bf16* Tr  = (__bf16*)smem;                 // epilogue alias [128][136] = 34816 B

  const int tid  = threadIdx.x;
  const int lane = tid & 63;
  const int w    = tid >> 6;
  const int quad = lane >> 4;
  const int l16  = lane & 15;
  const int wr   = w >> 1, wc = w & 1;
  const size_t m0 = (size_t)blockIdx.x * 128;   // M on x: same-A blocks share XCD
  const size_t n0 = (size_t)blockIdx.y * 128;

  f32x4 acc[4][4] = {};

  for (int k0 = 0; k0 < K; k0 += 64) {
#pragma unroll
    for (int it = 0; it < 4; ++it) {
      int slot = tid + it * 256;
      int row = slot >> 3, ch = slot & 7;
      async_copy16(A + (m0 + row) * K + k0 + ((ch ^ (row & 7)) * 8), &Ash[slot * 8]);
    }
#pragma unroll
    for (int it = 0; it < 4; ++it) {
      int slot = tid + it * 256;
      int row = slot >> 3, ch = slot & 7;
      async_copy16(Bm + (n0 + row) * K + k0 + ((ch ^ (row & 7)) * 8), &Bsh[slot * 8]);
    }
    __syncthreads();
#pragma unroll
    for (int kk = 0; kk < 2; ++kk) {
      bf16x8 af[4], bfr[4];
#pragma unroll
      for (int i = 0; i < 4; ++i) {
        int row = wr * 64 + i * 16 + l16;
        af[i] = *(const bf16x8*)&Ash[row * 64 + (((kk * 4 + quad) ^ (row & 7)) * 8)];
      }
#pragma unroll
      for (int j = 0; j < 4; ++j) {
        int row = wc * 64 + j * 16 + l16;
        bfr[j] = *(const bf16x8*)&Bsh[row * 64 + (((kk * 4 + quad) ^ (row & 7)) * 8)];
      }
#pragma unroll
      for (int i = 0; i < 4; ++i)
#pragma unroll
        for (int j = 0; j < 4; ++j)
          acc[i][j] = __builtin_amdgcn_mfma_f32_16x16x32_bf16(af[i], bfr[j], acc[i][j], 0, 0, 0);
    }
    __syncthreads();
  }

  if (zi != 2) {
    __bf16* C = (zi == 0) ? Qp : Kp;
#pragma unroll
    for (int i = 0; i < 4; ++i)
#pragma unroll
      for (int j = 0; j < 4; ++j)
#pragma unroll
        for (int r = 0; r < 4; ++r) {
          size_t row = m0 + wr * 64 + i * 16 + quad * 4 + r;
          size_t col = n0 + wc * 64 + j * 16 + l16;
          C[row * N + col] = (__bf16)acc[i][j][r];
        }
  } else {
    // transpose through LDS: Tr[d_local * 136 + s_local] (aliased; loop-end
    // __syncthreads already fenced the last Ash/Bsh reads)
#pragma unroll
    for (int i = 0; i < 4; ++i)
#pragma unroll
      for (int j = 0; j < 4; ++j)
#pragma unroll
        for (int r = 0; r < 4; ++r)
          Tr[(wc * 64 + j * 16 + l16) * 136 + (wr * 64 + i * 16 + quad * 4 + r)] =
              (__bf16)acc[i][j][r];
    __syncthreads();
    const int b_  = (int)(m0 >> 11);        // m0 / SEQ  (tile never crosses batch)
    const int sl0 = (int)(m0 & 2047);
#pragma unroll
    for (int it = 0; it < 8; ++it) {
      int slot = tid + it * 256;
      int d = slot >> 4, sc = slot & 15;
      *(int4*)&Vt[((size_t)(b_ * D_MODEL) + n0 + d) * SEQ + sl0 + sc * 8] =
          *(const int4*)&Tr[d * 136 + sc * 8];
    }
  }
}

// ---------------- out-proj GEMM (R3 body, proven) ----------------
__global__ __launch_bounds__(256, 2)
void gemm_out(const __bf16* __restrict__ A, const __bf16* __restrict__ Bm,
              float* __restrict__ C) {
  constexpr int BM = 64, BN = 128, K = D_MODEL, N = D_MODEL;
  __shared__ __bf16 Ash[BM * 64];   //  8 KB
  __shared__ __bf16 Bsh[BN * 64];   // 16 KB

  const int tid  = threadIdx.x;
  const int lane = tid & 63;
  const int w    = tid >> 6;
  const int quad = lane >> 4;
  const int l16  = lane & 15;
  const int wr   = w >> 1, wc = w & 1;
  const size_t m0 = (size_t)blockIdx.x * BM;
  const size_t n0 = (size_t)blockIdx.y * BN;

  f32x4 acc[2][4] = {};

  for (int k0 = 0; k0 < K; k0 += 64) {
#pragma unroll
    for (int it = 0; it < 2; ++it) {
      int slot = tid + it * 256;
      int row = slot >> 3, ch = slot & 7;
      async_copy16(A + (m0 + row) * K + k0 + ((ch ^ (row & 7)) * 8), &Ash[slot * 8]);
    }
#pragma unroll
    for (int it = 0; it < 4; ++it) {
      int slot = tid + it * 256;
      int row = slot >> 3, ch = slot & 7;
      async_copy16(Bm + (n0 + row) * K + k0 + ((ch ^ (row & 7)) * 8), &Bsh[slot * 8]);
    }
    __syncthreads();
#pragma unroll
    for (int kk = 0; kk < 2; ++kk) {
      bf16x8 af[2], bfr[4];
#pragma unroll
      for (int i = 0; i < 2; ++i) {
        int row = wr * 32 + i * 16 + l16;
        af[i] = *(const bf16x8*)&Ash[row * 64 + (((kk * 4 + quad) ^ (row & 7)) * 8)];
      }
#pragma unroll
      for (int j = 0; j < 4; ++j) {
        int row = wc * 64 + j * 16 + l16;
        bfr[j] = *(const bf16x8*)&Bsh[row * 64 + (((kk * 4 + quad) ^ (row & 7)) * 8)];
      }
#pragma unroll
      for (int i = 0; i < 2; ++i)
#pragma unroll
        for (int j = 0; j < 4; ++j)
          acc[i][j] = __builtin_amdgcn_mfma_f32_16x16x32_bf16(af[i], bfr[j], acc[i][j], 0, 0, 0);
    }
    __syncthreads();
  }

#pragma unroll
  for (int i = 0; i < 2; ++i)
#pragma unroll
    for (int j = 0; j < 4; ++j)
#pragma unroll
      for (int r = 0; r < 4; ++r) {
        size_t row = m0 + wr * 32 + i * 16 + quad * 4 + r;
        size_t col = n0 + wc * 64 + j * 16 + l16;
        C[row * N + col] = acc[i][j][r];
      }
}

// ---------------- causal flash attention ----------------
// R5: swapped QK^T (S^T = mfma(K,Q)) makes each lane hold P for its own
// q-column; with a consistent k-permutation of BOTH PV operands
// (k' = quad*8 + st*4 + r  <->  s = st*16 + quad*4 + r), the PV A-frag is
// built fully in-register (cvt_pk) and the Ps LDS round-trip (16 b16 writes
// + 2 b128 reads + lgkm wait per wave-iter) disappears. V reads become two
// ds_read_b64 per frag in the matching k'-order. LDS 32768 -> 4 blocks/CU,
// all 1024 blocks co-resident.
__global__ __launch_bounds__(256, 4)
void attn_kernel(const __bf16* __restrict__ Qp, const __bf16* __restrict__ Kp,
                 const __bf16* __restrict__ Vt, __bf16* __restrict__ Xo) {
  __shared__ __align__(16) char smem[32768];
  __bf16* Kb = (__bf16*)smem;                  // [2 dbuf][2 kd][64][32] = 16384 B
  __bf16* Vb = (__bf16*)(smem + 16384);        // [2 dbuf][2 sh][64][32] = 16384 B
  float*  Xch = (float*)smem;                  // epilogue alias [32][66] = 8448 B
  float*  Ls  = (float*)(smem + 8448);         // epilogue alias [2][32]  =  256 B

  const int tid  = threadIdx.x;
  const int lane = tid & 63;
  const int w    = tid >> 6;
  const int qh   = w >> 1, kh = w & 1;
  const int quad = lane >> 4;
  const int l16  = lane & 15;
  const int bh   = blockIdx.x;               // fastest -> XCD spread
  const int qt   = 31 - blockIdx.y;          // longest blocks dispatch first
  const int b    = bh >> 4, h = bh & 15;
  const int q0   = qt * 64;
  const size_t baseRow = (size_t)b * SEQ;
  const int colBase = h * DK;

  const int srow = w * 16 + (lane >> 2);
  const int sk   = (lane & 3) * 8;                         // linear LDS dest slot (gload_lds)
  const int skz  = (((lane & 3) ^ ((lane >> 3) & 3)) * 8); // inverse-swizzled GLOBAL source slot
  const int swz  = (l16 >> 1) & 3;                         // read-side 16B-slot XOR

  const float c1 = 0.18033688011f;           // 0.125 * log2(e)
  const float c2 = -23.083120654f;           // constant softmax shift

  bf16x8 aq[2][2];   // B-operand now: Q rows (mt), dk halves (kd)
  {
    const __bf16* qrow = Qp + (baseRow + q0 + qh * 32 + l16) * D_MODEL + colBase;
#pragma unroll
    for (int mt = 0; mt < 2; ++mt)
#pragma unroll
      for (int kd = 0; kd < 2; ++kd)
        aq[mt][kd] = *(const bf16x8*)(qrow + (size_t)mt * 16 * D_MODEL + kd * 32 + quad * 8);
  }

  f32x4 oacc[2][4] = {};
  float plsum[2] = {};

  // V b64 read offsets in k'-order (elements): own-quad s-slices {quad*4..+3, 16+quad*4..+3}
  const int e1 = (((quad >> 1) ^ swz) * 8) + (quad & 1) * 4;
  const int e2 = ((((quad >> 1) + 2) ^ swz) * 8) + (quad & 1) * 4;

  {  // prologue: stage j=0 into buf 0 (source pre-swizzled, LDS dest linear)
    const __bf16* kbase = Kp + (baseRow + srow) * D_MODEL + colBase + skz;
    async_copy16(kbase,      &Kb[0 * 2048 + srow * 32 + sk]);
    async_copy16(kbase + 32, &Kb[1 * 2048 + srow * 32 + sk]);
    const __bf16* vbase = Vt + ((size_t)b * D_MODEL + colBase + srow) * SEQ + skz;
    async_copy16(vbase,      &Vb[0 * 2048 + srow * 32 + sk]);
    async_copy16(vbase + 32, &Vb[1 * 2048 + srow * 32 + sk]);
  }

  for (int j = 0; j <= qt; ++j) {
    const int bf = j & 1;
    __syncthreads();

    if (j < qt) {
      const int nb = bf ^ 1;
      const __bf16* kbase = Kp + (baseRow + (size_t)(j + 1) * 64 + srow) * D_MODEL + colBase + skz;
      async_copy16(kbase,      &Kb[(nb * 2 + 0) * 2048 + srow * 32 + sk]);
      async_copy16(kbase + 32, &Kb[(nb * 2 + 1) * 2048 + srow * 32 + sk]);
      const __bf16* vbase = Vt + ((size_t)b * D_MODEL + colBase + srow) * SEQ + (size_t)(j + 1) * 64 + skz;
      async_copy16(vbase,      &Vb[(nb * 2 + 0) * 2048 + srow * 32 + sk]);
      async_copy16(vbase + 32, &Vb[(nb * 2 + 1) * 2048 + srow * 32 + sk]);
    }

    // ---- QK^T swapped: sacc[st][mt] = S^T; lane holds S[s=st*16+quad*4+r][q=mt*16+l16]
    f32x4 sacc[2][2] = {};
    __builtin_amdgcn_s_setprio(1);
#pragma unroll
    for (int kd = 0; kd < 2; ++kd) {
      bf16x8 bk0 = *(const bf16x8*)&Kb[(bf * 2 + kd) * 2048 + (kh * 32 + l16) * 32 + (quad ^ swz) * 8];
      bf16x8 bk1 = *(const bf16x8*)&Kb[(bf * 2 + kd) * 2048 + (kh * 32 + 16 + l16) * 32 + (quad ^ swz) * 8];
      sacc[0][0] = __builtin_amdgcn_mfma_f32_16x16x32_bf16(bk0, aq[0][kd], sacc[0][0], 0, 0, 0);
      sacc[0][1] = __builtin_amdgcn_mfma_f32_16x16x32_bf16(bk0, aq[1][kd], sacc[0][1], 0, 0, 0);
      sacc[1][0] = __builtin_amdgcn_mfma_f32_16x16x32_bf16(bk1, aq[0][kd], sacc[1][0], 0, 0, 0);
      sacc[1][1] = __builtin_amdgcn_mfma_f32_16x16x32_bf16(bk1, aq[1][kd], sacc[1][1], 0, 0, 0);
    }
    __builtin_amdgcn_s_setprio(0);

    // ---- softmax + in-register P pack (k' = st*4+r within own quad slice)
    const bool diag = (j == qt);
    bf16x8 pa[2];
#pragma unroll
    for (int mt = 0; mt < 2; ++mt)
#pragma unroll
      for (int st = 0; st < 2; ++st)
#pragma unroll
        for (int r = 0; r < 4; ++r) {
          float arg = fmaf(sacc[st][mt][r], c1, c2);
          if (diag) {
            int rowg = q0 + qh * 32 + mt * 16 + l16;
            int colg = j * 64 + kh * 32 + st * 16 + quad * 4 + r;
            if (colg > rowg) arg = -1e30f;
          }
          float p = __builtin_amdgcn_exp2f(arg);
          plsum[mt] += p;
          pa[mt][st * 4 + r] = (__bf16)p;
        }

    // ---- PV: A = pa (in-reg), B = V in matching k'-order (two b64 per frag)
    __builtin_amdgcn_s_setprio(1);
#pragma unroll
    for (int nt = 0; nt < 4; ++nt) {
      const int rowb = (bf * 2 + kh) * 2048 + (nt * 16 + l16) * 32;
      bf16x4 lo = *(const bf16x4*)&Vb[rowb + e1];
      bf16x4 hi = *(const bf16x4*)&Vb[rowb + e2];
      bf16x8 bv;
      bv[0] = lo[0]; bv[1] = lo[1]; bv[2] = lo[2]; bv[3] = lo[3];
      bv[4] = hi[0]; bv[5] = hi[1]; bv[6] = hi[2]; bv[7] = hi[3];
      oacc[0][nt] = __builtin_amdgcn_mfma_f32_16x16x32_bf16(pa[0], bv, oacc[0][nt], 0, 0, 0);
      oacc[1][nt] = __builtin_amdgcn_mfma_f32_16x16x32_bf16(pa[1], bv, oacc[1][nt], 0, 0, 0);
    }
    __builtin_amdgcn_s_setprio(0);
  }

  // L per q-row: sum the 4 quad-lanes holding partials for q = mt*16+l16
  float lred[2];
#pragma unroll
  for (int mt = 0; mt < 2; ++mt) {
    float l = plsum[mt];
    l += __shfl_xor(l, 16, 64);
    l += __shfl_xor(l, 32, 64);
    lred[mt] = l;
  }

#pragma unroll
  for (int mt = 0; mt < 2; ++mt) {   // FULLY UNROLLED (runtime mt index spills accumulators)
    __syncthreads();                 // fences Kb/Vb reads before alias writes
    if (kh == 1) {
#pragma unroll
      for (int nt = 0; nt < 4; ++nt)
#pragma unroll
        for (int r = 0; r < 4; ++r)
          Xch[(qh * 16 + quad * 4 + r) * 66 + nt * 16 + l16] = oacc[mt][nt][r];
    }
    if (quad == 0) Ls[kh * 32 + qh * 16 + l16] = lred[mt];
    __syncthreads();
    if (kh == 0) {
#pragma unroll
      for (int r = 0; r < 4; ++r) {
        float lt  = Ls[0 * 32 + qh * 16 + quad * 4 + r] + Ls[1 * 32 + qh * 16 + quad * 4 + r];
        float inv = 1.0f / lt;
        size_t row = baseRow + q0 + qh * 32 + mt * 16 + quad * 4 + r;
#pragma unroll
        for (int nt = 0; nt < 4; ++nt) {
          float o = oacc[mt][nt][r] + Xch[(qh * 16 + quad * 4 + r) * 66 + nt * 16 + l16];
          Xo[row * D_MODEL + colBase + nt * 16 + l16] = (__bf16)(o * inv);
        }
      }
    }
  }
}

// ---------------- launch ----------------
extern "C" void kernel_launch(void* const* d_in, const int* in_sizes, int n_in,
                              void* d_out, int out_size, void* d_ws, size_t ws_size,
                              hipStream_t stream) {
  const float* q  = (const float*)d_in[0];
  const float* k  = (const float*)d_in[1];
  const float* v  = (const float*)d_in[2];
  const float* wq = (const float*)d_in[3];
  const float* wk = (const float*)d_in[4];
  const float* wv = (const float*)d_in[5];
  const float* wo = (const float*)d_in[6];
  float* out = (float*)d_out;

  const size_t MD = (size_t)BATCH * SEQ * D_MODEL;
  const size_t WD = (size_t)D_MODEL * D_MODEL;
  __bf16* ws  = (__bf16*)d_ws;
  __bf16* Qp  = ws;
  __bf16* Kp  = Qp + MD;
  __bf16* Vt  = Kp + MD;
  __bf16* Xa  = Vt + MD;
  __bf16* qbf = Xa + MD;
  __bf16* kbf = qbf + MD;
  __bf16* vbf = kbf + MD;
  __bf16* wqb = vbf + MD;
  __bf16* wkb = wqb + WD;
  __bf16* wvb = wkb + WD;
  __bf16* wob = wvb + WD;

  // 1) casts: 3*MD/4 + 4*WD/4 = 4 Mi float4 -> 16384 blocks
  cast_all<<<16384, 256, 0, stream>>>(q, k, v, wq, wk, wv, wo,
                                      qbf, kbf, vbf, wqb, wkb, wvb, wob);

  // 2) Q/K/V projections (V written directly transposed)
  gemm_proj<<<dim3(32, 8, 3), 256, 0, stream>>>(
      qbf, kbf, vbf, wqb, wkb, wvb, Qp, Kp, Vt);

  // 3) causal attention: 1024 blocks (bh fastest, qt descending), 4/CU all-resident
  attn_kernel<<<dim3(BATCH * NHEADS, 32), 256, 0, stream>>>(Qp, Kp, Vt, Xa);

  // 4) output projection -> f32 out
  gemm_out<<<dim3(64, 8), 256, 0, stream>>>(Xa, wob, out);
}